// Round 9
// baseline (11259.821 us; speedup 1.0000x reference)
//
#include <hip/hip_runtime.h>

#define Bsz 128
#define Ssz 1024
#define Isz 256
#define Hsz 512
#define GW  16      // workgroups per group
#define NG  8       // groups (16 sequences each)

typedef _Float16 half8v __attribute__((ext_vector_type(8)));
typedef float f32x4 __attribute__((ext_vector_type(4)));

#define XBUF_SZ (16*Isz*2)                    // 8 KiB per group-buffer (16 rows x 256 f16)
#define HBUF_SZ (16*Hsz*2)                    // 16 KiB per group-buffer
#define XBUF_OFF 4096                          // counters live in [0,4096)
#define HBUF_OFF (XBUF_OFF + NG*2*XBUF_SZ)     // 4096 + 131072

__global__ void qmog_init(int* cnt) {
  // release-at-agent store: visible to all XCDs' acquire loads (G16)
  __hip_atomic_store(&cnt[threadIdx.x], 0, __ATOMIC_RELEASE, __HIP_MEMORY_SCOPE_AGENT);
}

__device__ __forceinline__ float sigmoidf_(float v) {
  return 1.f / (1.f + __expf(-v));
}
__device__ __forceinline__ float tanhf_(float v) {
  // overflow-safe tanh via exp(-2|v|)
  float a = fabsf(v);
  float e = __expf(-2.f * a);
  float r = (1.f - e) / (1.f + e);
  return v < 0.f ? -r : r;
}
// XOR swizzle (G4/T2): breaks the 16-way bank conflict of power-of-2 row strides
__device__ __forceinline__ int hswz(int row, int kb) { return row*1024 + (kb ^ ((row&7)<<4)); }
__device__ __forceinline__ int xswz(int row, int kb) { return row*512  + (kb ^ ((row&7)<<4)); }

__device__ __forceinline__ half8v cvt8(f32x4 a, f32x4 b) {
  half8v r;
  r[0]=(_Float16)a[0]; r[1]=(_Float16)a[1]; r[2]=(_Float16)a[2]; r[3]=(_Float16)a[3];
  r[4]=(_Float16)b[0]; r[5]=(_Float16)b[1]; r[6]=(_Float16)b[2]; r[7]=(_Float16)b[3];
  return r;
}

// 128 persistent wgs (cooperative launch: co-residency guaranteed; plain-launch
// fallback is safe in practice at 128 wgs / 256 CUs with 2 blocks/CU bounds).
// group g = bid&7, wid = bid>>3 owns h-columns [wid*32,+32) of each gate and
// mod cols [wid*16,+16).
__global__ __launch_bounds__(512, 2)
void qmog_main(const float* __restrict__ x, const float* __restrict__ delta,
               const float* __restrict__ Wm, const float* __restrict__ bm,
               const float* __restrict__ Wih, const float* __restrict__ bih,
               const float* __restrict__ Whh, const float* __restrict__ bhh,
               float* __restrict__ out, char* __restrict__ ws) {
  const int tid  = threadIdx.x;
  const int lane = tid & 63;
  const int wv   = tid >> 6;      // wave 0..7
  const int bid  = blockIdx.x;    // 0..127
  const int g    = bid & 7;
  const int wid  = bid >> 3;      // 0..15

  __shared__ char hlds[16*1024];       // 16 rows x 512 f16, swizzled
  __shared__ char xlds[16*512];        // 16 rows x 256 f16, swizzled
  __shared__ float tiles[8][16][17];   // +1 pad: mod partials, then gate tiles

  int* xcnt = (int*)(ws + (size_t)(g*2+0)*128);
  int* hcnt = (int*)(ws + (size_t)(g*2+1)*128);

  // ---- prologue: weights -> f16 register fragments (held for all 1024 steps) ----
  // wave wv: gate = wv>>1, half = wv&1 -> 16 gate columns; B-frag: lane supplies
  // W[colbase+(l&15)][kc*32 + (l>>4)*8 + j]  (W is (N,K) row-major = PyTorch layout)
  half8v gw[24];   // kc 0..7: W_ih (K=256); kc 8..23: W_hh (K=512)   ~96 VGPR
  {
    const int gate   = wv >> 1;
    const int colrow = gate*Hsz + wid*32 + (wv&1)*16 + (lane & 15);
    const int ko     = (lane >> 4) * 8;
    const float* pih = Wih + (size_t)colrow*Isz + ko;
    const float* phh = Whh + (size_t)colrow*Hsz + ko;
#pragma unroll
    for (int kc = 0; kc < 8; kc++)
      gw[kc] = cvt8(*(const f32x4*)(pih + kc*32), *(const f32x4*)(pih + kc*32 + 4));
#pragma unroll
    for (int kc = 0; kc < 16; kc++)
      gw[8+kc] = cvt8(*(const f32x4*)(phh + kc*32), *(const f32x4*)(phh + kc*32 + 4));
  }
  half8v mw[2];  // mod K-split: wave wv covers k-chunks 2wv,2wv+1
  {
    const int mrow = wid*16 + (lane & 15);
    const float* pm = Wm + (size_t)mrow*(Hsz+1) + (lane>>4)*8;
#pragma unroll
    for (int j = 0; j < 2; j++) {
      const float* p = pm + (2*wv + j)*32;
      half8v r;
#pragma unroll
      for (int e = 0; e < 8; e++) r[e] = (_Float16)p[e];
      mw[j] = r;
    }
  }
  const int hcol = wid*32 + (tid & 31);          // this thread's h-column (cell update)
  const float bI = bih[hcol]       + bhh[hcol];
  const float bF = bih[Hsz+hcol]   + bhh[Hsz+hcol];
  const float bG = bih[2*Hsz+hcol] + bhh[2*Hsz+hcol];
  const float bO = bih[3*Hsz+hcol] + bhh[3*Hsz+hcol];
  const int mcol = wid*16 + (tid & 15);          // this thread's mod column (tid<256)
  const float bM  = bm[mcol];
  const float wmd = Wm[(size_t)mcol*(Hsz+1) + Hsz];  // delta column of W_m
  const int rm = tid >> 4;                        // mod row (tid<256)

#pragma unroll
  for (int p = 0; p < 2; p++)                     // h0 = 0
    *(f32x4*)(hlds + tid*32 + p*16) = (f32x4){0.f,0.f,0.f,0.f};
  float cC = 0.f;                                 // c0 = 0 (one element per thread)
  __syncthreads();

  const int arow = lane & 15;            // A-frag: row = l&15, k = (l>>4)*8 + j
  const int akb  = (lane >> 4) * 16;

  // x/delta prefetch for t=0 (one step ahead thereafter)
  float xv = 0.f, dv = 0.f;
  if (tid < 256) {
    const int b = g*16 + rm;
    xv = x[(size_t)b*Ssz*Isz + mcol];
    dv = delta[(size_t)b*Ssz];
  }

  for (int t = 0; t < Ssz; ++t) {
    _Float16* xb = (_Float16*)(ws + XBUF_OFF + (size_t)(g*2 + (t&1))*XBUF_SZ);
    _Float16* hb = (_Float16*)(ws + HBUF_OFF + (size_t)(g*2 + (t&1))*HBUF_SZ);

    // ---- phase 1: modulation slice (K=512 split over 8 waves, LDS reduce) ----
    f32x4 macc = {0.f,0.f,0.f,0.f};
#pragma unroll
    for (int j = 0; j < 2; j++) {
      const int kc = 2*wv + j;
      half8v a = *(const half8v*)(hlds + hswz(arow, kc*64 + akb));
      macc = __builtin_amdgcn_mfma_f32_16x16x32_f16(a, mw[j], macc, 0, 0, 0);
    }
#pragma unroll
    for (int q = 0; q < 4; q++)           // C layout: col=l&15, row=(l>>4)*4+q
      tiles[wv][(lane>>4)*4 + q][lane & 15] = macc[q];
    __syncthreads();

    if (tid < 256) {
      float s = bM + dv * wmd;
#pragma unroll
      for (int w = 0; w < 8; w++) s += tiles[w][rm][tid & 15];
      // xt = sigmoid(mod_pre) * x_t  -> publish f16 slice (contiguous 512B per wg)
      xb[wid*256 + rm*16 + (tid & 15)] = (_Float16)(sigmoidf_(s) * xv);
    }
    __syncthreads();                      // drain all waves' xb stores before release
    if (tid == 0)
      __hip_atomic_fetch_add(xcnt, 1, __ATOMIC_RELEASE, __HIP_MEMORY_SCOPE_AGENT);

    // prefetch x/delta for t+1 (no dependency; lands during this step's MFMAs+barriers)
    if (tid < 256 && t + 1 < Ssz) {
      const int b = g*16 + rm;
      xv = x[((size_t)b*Ssz + (t+1))*Isz + mcol];
      dv = delta[(size_t)b*Ssz + (t+1)];
    }

    // ---- phase 2a: gates h-part (16 MFMA) — hides barrier #1 latency ----
    f32x4 gacc = {0.f,0.f,0.f,0.f};
#pragma unroll
    for (int kc = 0; kc < 16; kc++) {
      half8v a = *(const half8v*)(hlds + hswz(arow, kc*64 + akb));
      gacc = __builtin_amdgcn_mfma_f32_16x16x32_f16(a, gw[8+kc], gacc, 0, 0, 0);
    }

    if (tid == 0) {                       // wait for all 16 wgs' xt slices
      const int target = GW*(t+1);
      while (__hip_atomic_load(xcnt, __ATOMIC_ACQUIRE, __HIP_MEMORY_SCOPE_AGENT) < target)
        __builtin_amdgcn_s_sleep(1);
    }
    __syncthreads();

    {                                     // gather full xt (16x256 f16) -> swizzled LDS
      const int idx  = tid*16;
      f32x4 v = *(const f32x4*)((const char*)xb + idx);
      const int wsrc = idx >> 9;
      const int row  = (idx >> 5) & 15;
      const int colb = idx & 31;
      *(f32x4*)(xlds + xswz(row, wsrc*32 + colb)) = v;
    }
    __syncthreads();

    // ---- phase 2b: gates x-part (8 MFMA) ----
#pragma unroll
    for (int kc = 0; kc < 8; kc++) {
      half8v a = *(const half8v*)(xlds + xswz(arow, kc*64 + akb));
      gacc = __builtin_amdgcn_mfma_f32_16x16x32_f16(a, gw[kc], gacc, 0, 0, 0);
    }
#pragma unroll
    for (int q = 0; q < 4; q++)
      tiles[wv][(lane>>4)*4 + q][lane & 15] = gacc[q];
    __syncthreads();

    // ---- phase 3: LSTM cell (512 threads = 16 rows x 32 h-cols) ----
    {
      const int r = tid >> 5, cj = tid & 31;
      const int th = cj >> 4, cl = cj & 15;       // tile = gate*2 + th
      const float gi = tiles[0+th][r][cl] + bI;
      const float gf = tiles[2+th][r][cl] + bF;
      const float gg = tiles[4+th][r][cl] + bG;
      const float go = tiles[6+th][r][cl] + bO;
      const float fi = sigmoidf_(gi);
      const float ff = sigmoidf_(gf);
      const float fo = sigmoidf_(go);
      cC = ff*cC + fi*tanhf_(gg);
      const float hN = fo * tanhf_(cC);
      const int b = g*16 + r;
      __builtin_nontemporal_store(hN, out + ((size_t)b*Ssz + t)*Hsz + hcol);
      if (t == Ssz-1)
        out[(size_t)Bsz*Ssz*Hsz + (size_t)b*Hsz + hcol] = hN;   // h_fin
      hb[wid*512 + r*32 + cj] = (_Float16)hN;     // contiguous 1KiB per wg (no false sharing)
    }
    __syncthreads();                      // drain hb/out stores before release
    if (tid == 0) {
      __hip_atomic_fetch_add(hcnt, 1, __ATOMIC_RELEASE, __HIP_MEMORY_SCOPE_AGENT);
      const int target = GW*(t+1);
      while (__hip_atomic_load(hcnt, __ATOMIC_ACQUIRE, __HIP_MEMORY_SCOPE_AGENT) < target)
        __builtin_amdgcn_s_sleep(1);
    }
    __syncthreads();

    {                                     // gather full h (16x512 f16) -> swizzled LDS
#pragma unroll
      for (int p = 0; p < 2; p++) {
        const int idx  = tid*32 + p*16;
        f32x4 v = *(const f32x4*)((const char*)hb + idx);
        const int wsrc = idx >> 10;
        const int row  = (idx >> 6) & 15;
        const int colb = idx & 63;
        *(f32x4*)(hlds + hswz(row, wsrc*64 + colb)) = v;
      }
    }
    __syncthreads();
  }
}

extern "C" void kernel_launch(void* const* d_in, const int* in_sizes, int n_in,
                              void* d_out, int out_size, void* d_ws, size_t ws_size,
                              hipStream_t stream) {
  const float* x   = (const float*)d_in[0];
  const float* dl  = (const float*)d_in[1];
  const float* Wm  = (const float*)d_in[2];
  const float* bm  = (const float*)d_in[3];
  const float* Wih = (const float*)d_in[4];
  const float* bih = (const float*)d_in[5];
  const float* Whh = (const float*)d_in[6];
  const float* bhh = (const float*)d_in[7];
  float* out = (float*)d_out;
  char*  ws  = (char*)d_ws;

  qmog_init<<<1, 1024, 0, stream>>>((int*)d_ws);

  void* args[] = { (void*)&x, (void*)&dl, (void*)&Wm, (void*)&bm,
                   (void*)&Wih, (void*)&bih, (void*)&Whh, (void*)&bhh,
                   (void*)&out, (void*)&ws };
  hipError_t e = hipLaunchCooperativeKernel((const void*)qmog_main, dim3(128),
                                            dim3(512), args, 0, stream);
  if (e != hipSuccess) {
    // fallback: plain launch (co-residency is physically guaranteed at
    // 128 wgs / 256 CUs with __launch_bounds__(512,2))
    qmog_main<<<128, 512, 0, stream>>>(x, dl, Wm, bm, Wih, bih, Whh, bhh, out, ws);
  }
}